// Round 7
// baseline (262.427 us; speedup 1.0000x reference)
//
#include <hip/hip_runtime.h>
#include <hip/hip_bf16.h>

typedef __attribute__((ext_vector_type(8))) short short8;
typedef __attribute__((ext_vector_type(4))) float f32x4;

#define H_DIM 768
#define E_EXP 16
#define T_TASK 8
#define KSEL 4
#define L_SEQ 8192
#define B_BATCH 16
#define EW_STRIDE (768*768)

#define WCT_BLOCKS 576     // 24 x 24 tiles of 32x32
#define CVT_BLOCKS 384     // x[0] f32 -> bf16, grid-stride
#define GEMM_BLOCKS 384    // 64 m-strips x 6 n-tiles (m-outer)
#define FILL_BLOCKS 704    // batches 1..15 (377 MB) — the BW backbone
#define TOTAL_BLOCKS (WCT_BLOCKS + CVT_BLOCKS + GEMM_BLOCKS + FILL_BLOCKS)  // 2048

#define WS_X0B_OFF (2 * EW_STRIDE)        // after 1.18 MB wct
#define WS_FLAG_OFF (16 * 1024 * 1024)    // flags at 16 MB

// 16 KB LDS union: GEMM staging vs gating/wct scratch
union SMemU {
  struct {
    unsigned short As[128 * 32];   // 8 KB
    unsigned short Bs[128 * 32];   // 8 KB
  } g;
  struct {
    float logits[T_TASK][E_EXP];
    float g_sh[KSEL];
    int   i_sh[KSEL];
    float tile[32][33];
  } w;
};

__device__ __forceinline__ void gload_lds16(const void* g, void* l) {
  __builtin_amdgcn_global_load_lds((const __attribute__((address_space(1))) void*)g,
                                   (__attribute__((address_space(3))) void*)l, 16, 0, 0);
}

__global__ __launch_bounds__(256) void mega2_kernel(
    const float* __restrict__ x,          // x[0] = first 8192*768 floats
    const float* __restrict__ task_full,
    const float* __restrict__ gate_w,
    const float* __restrict__ gate_b,
    const float* __restrict__ expert_w,
    __hip_bfloat16* __restrict__ wct,     // ws [768][768] bf16, o-major
    __hip_bfloat16* __restrict__ x0b,     // ws [8192][768] bf16
    int* __restrict__ flags,              // ws: {wct_done, cvt_done}, memset 0
    float* __restrict__ out,
    float* __restrict__ out_tail) {
  __shared__ SMemU sm;
  const int bid = blockIdx.x;
  const int tid = threadIdx.x;

  if (bid < WCT_BLOCKS) {
    // ============ gating (redundant per block, deterministic) ==============
    // logits[t][e] = sum_h silu(tf[t][h]) * gw[h][e]; t = tid>>5, 32 lanes/t
    {
      const int t = tid >> 5, l = tid & 31;
      float accv[E_EXP];
#pragma unroll
      for (int e = 0; e < E_EXP; ++e) accv[e] = 0.f;
      for (int h = l; h < H_DIM; h += 32) {
        float v = task_full[t * H_DIM + h];
        const float s = v / (1.f + expf(-v));
        const float* gw = &gate_w[h * E_EXP];
#pragma unroll
        for (int e = 0; e < E_EXP; ++e) accv[e] += s * gw[e];
      }
#pragma unroll
      for (int off = 16; off; off >>= 1)
#pragma unroll
        for (int e = 0; e < E_EXP; ++e)
          accv[e] += __shfl_xor(accv[e], off, 32);
      if (l == 0)
#pragma unroll
        for (int e = 0; e < E_EXP; ++e)
          sm.w.logits[t][e] = accv[e] + gate_b[e];
    }
    __syncthreads();
    if (tid < T_TASK) {
      const int t = tid;
      float p[E_EXP];
      float m = -1e30f;
      for (int e = 0; e < E_EXP; ++e) m = fmaxf(m, sm.w.logits[t][e]);
      float s = 0.f;
      for (int e = 0; e < E_EXP; ++e) { p[e] = expf(sm.w.logits[t][e] - m); s += p[e]; }
      const float inv = 1.f / s;
      for (int e = 0; e < E_EXP; ++e) p[e] *= inv;
      bool used[E_EXP];
      for (int e = 0; e < E_EXP; ++e) used[e] = false;
      float g[KSEL]; int sel[KSEL];
      for (int k = 0; k < KSEL; ++k) {
        float bv = -1.f; int bi = 0;
        for (int e = 0; e < E_EXP; ++e)
          if (!used[e] && p[e] > bv) { bv = p[e]; bi = e; }
        used[bi] = true; sel[k] = bi; g[k] = bv;
      }
      if (bid == 0) {
        for (int e = 0; e < E_EXP; ++e)
          out_tail[E_EXP + t * E_EXP + e] = used[e] ? 1.f : 0.f;
        if (t == 0)
          for (int e = 0; e < E_EXP; ++e) out_tail[e] = p[e];
      }
      if (t == 0)
        for (int k = 0; k < KSEL; ++k) { sm.w.g_sh[k] = g[k]; sm.w.i_sh[k] = sel[k]; }
    }
    __syncthreads();
    // ============ wct tile: wct[o][d] = sum_k g_k * W[idx_k][d][o] =========
    const float g0 = sm.w.g_sh[0], g1 = sm.w.g_sh[1], g2 = sm.w.g_sh[2], g3 = sm.w.g_sh[3];
    const size_t e0 = (size_t)sm.w.i_sh[0] * EW_STRIDE;
    const size_t e1 = (size_t)sm.w.i_sh[1] * EW_STRIDE;
    const size_t e2 = (size_t)sm.w.i_sh[2] * EW_STRIDE;
    const size_t e3 = (size_t)sm.w.i_sh[3] * EW_STRIDE;
    const int d0 = (bid % 24) * 32, o0 = (bid / 24) * 32;
    const int c = tid & 31;
    const int r0 = tid >> 5;  // 0..7
#pragma unroll
    for (int it = 0; it < 4; ++it) {
      const int rr = it * 8 + r0;  // d offset
      const size_t off = (size_t)(d0 + rr) * H_DIM + o0 + c;
      sm.w.tile[rr][c] = g0 * expert_w[e0 + off] + g1 * expert_w[e1 + off] +
                         g2 * expert_w[e2 + off] + g3 * expert_w[e3 + off];
    }
    __syncthreads();
#pragma unroll
    for (int it = 0; it < 4; ++it) {
      const int rr = it * 8 + r0;  // o offset
      wct[(size_t)(o0 + rr) * H_DIM + d0 + c] = __float2bfloat16(sm.w.tile[c][rr]);
    }
    __threadfence();
    __syncthreads();
    if (tid == 0)
      __hip_atomic_fetch_add(&flags[0], 1, __ATOMIC_RELEASE, __HIP_MEMORY_SCOPE_AGENT);

  } else if (bid < WCT_BLOCKS + CVT_BLOCKS) {
    // ============ x[0] f32 -> bf16 (grid-stride) ===========================
    const int cb = bid - WCT_BLOCKS;
    const float4* xv = (const float4*)x;
    uint4* xo = (uint4*)x0b;
    const int n8 = L_SEQ * H_DIM / 8;          // 786432 uint4
    const int stride = CVT_BLOCKS * 256;
    for (int i = cb * 256 + tid; i < n8; i += stride) {
      const float4 a = xv[2 * i];
      const float4 b = xv[2 * i + 1];
      alignas(16) __hip_bfloat16 h[8];
      h[0] = __float2bfloat16(a.x); h[1] = __float2bfloat16(a.y);
      h[2] = __float2bfloat16(a.z); h[3] = __float2bfloat16(a.w);
      h[4] = __float2bfloat16(b.x); h[5] = __float2bfloat16(b.y);
      h[6] = __float2bfloat16(b.z); h[7] = __float2bfloat16(b.w);
      xo[i] = *(const uint4*)h;
    }
    __threadfence();
    __syncthreads();
    if (tid == 0)
      __hip_atomic_fetch_add(&flags[1], 1, __ATOMIC_RELEASE, __HIP_MEMORY_SCOPE_AGENT);

  } else if (bid < WCT_BLOCKS + CVT_BLOCKS + GEMM_BLOCKS) {
    // ============ GEMM: C[l][o] = 1 + sum_d A[l][d]*wct[o][d] ==============
    if (tid == 0) {
      while (__hip_atomic_load(&flags[0], __ATOMIC_ACQUIRE, __HIP_MEMORY_SCOPE_AGENT) < WCT_BLOCKS ||
             __hip_atomic_load(&flags[1], __ATOMIC_ACQUIRE, __HIP_MEMORY_SCOPE_AGENT) < CVT_BLOCKS)
        __builtin_amdgcn_s_sleep(2);
    }
    __syncthreads();
    __hip_bfloat16* As = (__hip_bfloat16*)sm.g.As;
    __hip_bfloat16* Bs = (__hip_bfloat16*)sm.g.Bs;
    const int gb = bid - WCT_BLOCKS - CVT_BLOCKS;
    const int m0 = (gb / 6) * 128;   // m-outer: 6 consecutive bids share A strip
    const int n0 = (gb % 6) * 128;
    const int lane = tid & 63;
    const int w = tid >> 6;
    const int wr = w >> 1, wc = w & 1;      // 2x2 waves, 64x64 each
    const int r = tid >> 2, s = tid & 3;    // staging: row, 16B chunk
    const __hip_bfloat16* ga = x0b + (size_t)(m0 + r) * H_DIM + s * 8;
    const __hip_bfloat16* gbp = wct + (size_t)(n0 + r) * H_DIM + s * 8;
    f32x4 acc[4][4] = {};
    const int arow = wr * 64 + (lane & 15);
    const int brow = wc * 64 + (lane & 15);
    const int koff = (lane >> 4) * 8;  // same k map for A and B -> k-perm safe
    for (int k0 = 0; k0 < H_DIM; k0 += 32) {
      gload_lds16(ga + k0,               &As[tid * 8]);
      gload_lds16(ga + 64 * H_DIM + k0,  &As[2048 + tid * 8]);
      gload_lds16(gbp + k0,              &Bs[tid * 8]);
      gload_lds16(gbp + 64 * H_DIM + k0, &Bs[2048 + tid * 8]);
      __syncthreads();
      short8 av[4], bv[4];
#pragma unroll
      for (int i = 0; i < 4; ++i) av[i] = *(const short8*)&As[(arow + i * 16) * 32 + koff];
#pragma unroll
      for (int j = 0; j < 4; ++j) bv[j] = *(const short8*)&Bs[(brow + j * 16) * 32 + koff];
#pragma unroll
      for (int i = 0; i < 4; ++i)
#pragma unroll
        for (int j = 0; j < 4; ++j)
          acc[i][j] = __builtin_amdgcn_mfma_f32_16x16x32_bf16(av[i], bv[j], acc[i][j], 0, 0, 0);
      __syncthreads();
    }
    const int crow0 = m0 + wr * 64 + (lane >> 4) * 4;
    const int ccol0 = n0 + wc * 64 + (lane & 15);
#pragma unroll
    for (int i = 0; i < 4; ++i)
#pragma unroll
      for (int j = 0; j < 4; ++j)
#pragma unroll
        for (int q = 0; q < 4; ++q)
          out[(size_t)(crow0 + i * 16 + q) * H_DIM + ccol0 + j * 16] = 1.0f + acc[i][j][q];

  } else {
    // ============ fill batches 1..15 with 1.0 (plain stores) ===============
    const int fb = bid - WCT_BLOCKS - CVT_BLOCKS - GEMM_BLOCKS;
    f32x4* p = (f32x4*)(out + (size_t)L_SEQ * H_DIM);
    const size_t n4 = (size_t)(B_BATCH - 1) * L_SEQ * H_DIM / 4;  // 23592960
    size_t i = (size_t)fb * 256 + tid;
    const size_t stride = (size_t)FILL_BLOCKS * 256;
    const f32x4 one = {1.f, 1.f, 1.f, 1.f};
    for (; i < n4; i += stride) p[i] = one;
  }
}

// ---------------------------------------------------------------- launch ----
extern "C" void kernel_launch(void* const* d_in, const int* in_sizes, int n_in,
                              void* d_out, int out_size, void* d_ws, size_t ws_size,
                              hipStream_t stream) {
  const float* x         = (const float*)d_in[0];  // [16][8192][768]
  const float* task_full = (const float*)d_in[1];  // [8][768]
  const float* gate_w    = (const float*)d_in[2];  // [768][16]
  const float* gate_b    = (const float*)d_in[3];  // [16]
  const float* expert_w  = (const float*)d_in[4];  // [16][768][768]
  float* out = (float*)d_out;

  const size_t n_out_main = (size_t)B_BATCH * L_SEQ * H_DIM;  // 100663296
  float* out_tail = out + n_out_main;

  __hip_bfloat16* wct = (__hip_bfloat16*)d_ws;
  __hip_bfloat16* x0b = (__hip_bfloat16*)((char*)d_ws + WS_X0B_OFF);
  int* flags = (int*)((char*)d_ws + WS_FLAG_OFF);

  hipMemsetAsync((void*)flags, 0, 2 * sizeof(int), stream);
  mega2_kernel<<<TOTAL_BLOCKS, 256, 0, stream>>>(
      x, task_full, gate_w, gate_b, expert_w, wct, x0b, flags, out, out_tail);
}

// Round 8
// 126.446 us; speedup vs baseline: 2.0754x; 2.0754x over previous
//
#include <hip/hip_runtime.h>
#include <hip/hip_bf16.h>

typedef __attribute__((ext_vector_type(8))) short short8;
typedef __attribute__((ext_vector_type(4))) float f32x4;

#define H_DIM 768
#define E_EXP 16
#define T_TASK 8
#define KSEL 4
#define L_SEQ 8192
#define B_BATCH 16
#define EW_STRIDE (768*768)

#define CVT_BLOCKS 3072    // (8192*768/8)/256 uint4 stores
#define WCT_BLOCKS 576     // 24 x 24 tiles of 32x32
#define FILL1_BLOCKS 1408  // batches 1..8 (201.3 MB)
#define GEMM_BLOCKS 768    // 64 m-strips x 12 n-tiles (128x64), m-outer
#define FILL2_BLOCKS 1472  // batches 9..15 (176.2 MB)

// ------------------------------------------------------------------ K1 ------
// (unchanged from the 119us round-5 kernel)
__global__ __launch_bounds__(256) void k1_cvt_wct_fill(
    const float4* __restrict__ x,
    const float* __restrict__ task_full,
    const float* __restrict__ gate_w,
    const float* __restrict__ gate_b,
    const float* __restrict__ expert_w,
    __hip_bfloat16* __restrict__ wct,
    uint4* __restrict__ xb,
    float* __restrict__ out_tail,
    float4* __restrict__ fill_p, size_t fill_n4) {
  const int bid = blockIdx.x;
  const int tid = threadIdx.x;
  if (bid < CVT_BLOCKS) {
    const int i = bid * 256 + tid;  // one uint4 = 8 bf16
    const float4 a = x[2 * i];
    const float4 b = x[2 * i + 1];
    alignas(16) __hip_bfloat16 h[8];
    h[0] = __float2bfloat16(a.x); h[1] = __float2bfloat16(a.y);
    h[2] = __float2bfloat16(a.z); h[3] = __float2bfloat16(a.w);
    h[4] = __float2bfloat16(b.x); h[5] = __float2bfloat16(b.y);
    h[6] = __float2bfloat16(b.z); h[7] = __float2bfloat16(b.w);
    xb[i] = *(const uint4*)h;
  } else if (bid < CVT_BLOCKS + WCT_BLOCKS) {
    __shared__ float silu_s[T_TASK * H_DIM];
    __shared__ float logits[T_TASK][E_EXP];
    __shared__ float g_sh[KSEL];
    __shared__ int   i_sh[KSEL];
    __shared__ float tile[32][33];
    const int wb = bid - CVT_BLOCKS;
    for (int i = tid; i < T_TASK * H_DIM; i += 256) {
      float v = task_full[i];
      silu_s[i] = v / (1.f + expf(-v));
    }
    __syncthreads();
    if (tid < T_TASK * E_EXP) {
      const int t = tid >> 4, e = tid & 15;
      float a0 = 0.f, a1 = 0.f, a2 = 0.f, a3 = 0.f;
      const float* sl = &silu_s[t * H_DIM];
      for (int h = 0; h < H_DIM; h += 4) {
        a0 += sl[h]     * gate_w[(h)     * E_EXP + e];
        a1 += sl[h + 1] * gate_w[(h + 1) * E_EXP + e];
        a2 += sl[h + 2] * gate_w[(h + 2) * E_EXP + e];
        a3 += sl[h + 3] * gate_w[(h + 3) * E_EXP + e];
      }
      logits[t][e] = (a0 + a1) + (a2 + a3) + gate_b[e];
    }
    __syncthreads();
    if (tid < T_TASK) {
      const int t = tid;
      float p[E_EXP];
      float m = -1e30f;
      for (int e = 0; e < E_EXP; ++e) m = fmaxf(m, logits[t][e]);
      float s = 0.f;
      for (int e = 0; e < E_EXP; ++e) { p[e] = expf(logits[t][e] - m); s += p[e]; }
      const float inv = 1.f / s;
      for (int e = 0; e < E_EXP; ++e) p[e] *= inv;
      bool used[E_EXP];
      for (int e = 0; e < E_EXP; ++e) used[e] = false;
      float g[KSEL]; int sel[KSEL];
      for (int k = 0; k < KSEL; ++k) {
        float bv = -1.f; int bi = 0;
        for (int e = 0; e < E_EXP; ++e)
          if (!used[e] && p[e] > bv) { bv = p[e]; bi = e; }
        used[bi] = true; sel[k] = bi; g[k] = bv;
      }
      if (wb == 0) {
        for (int e = 0; e < E_EXP; ++e)
          out_tail[E_EXP + t * E_EXP + e] = used[e] ? 1.f : 0.f;
        if (t == 0)
          for (int e = 0; e < E_EXP; ++e) out_tail[e] = p[e];
      }
      if (t == 0)
        for (int k = 0; k < KSEL; ++k) { g_sh[k] = g[k]; i_sh[k] = sel[k]; }
    }
    __syncthreads();
    const float g0 = g_sh[0], g1 = g_sh[1], g2 = g_sh[2], g3 = g_sh[3];
    const size_t e0 = (size_t)i_sh[0] * EW_STRIDE;
    const size_t e1 = (size_t)i_sh[1] * EW_STRIDE;
    const size_t e2 = (size_t)i_sh[2] * EW_STRIDE;
    const size_t e3 = (size_t)i_sh[3] * EW_STRIDE;
    const int d0 = (wb % 24) * 32, o0 = (wb / 24) * 32;
    const int c = tid & 31;
    const int r0 = tid >> 5;  // 0..7
#pragma unroll
    for (int it = 0; it < 4; ++it) {
      const int rr = it * 8 + r0;  // d offset
      const size_t off = (size_t)(d0 + rr) * H_DIM + o0 + c;
      tile[rr][c] = g0 * expert_w[e0 + off] + g1 * expert_w[e1 + off] +
                    g2 * expert_w[e2 + off] + g3 * expert_w[e3 + off];
    }
    __syncthreads();
#pragma unroll
    for (int it = 0; it < 4; ++it) {
      const int rr = it * 8 + r0;  // o offset
      wct[(size_t)(o0 + rr) * H_DIM + d0 + c] = __float2bfloat16(tile[c][rr]);
    }
  } else {
    const int fb = bid - CVT_BLOCKS - WCT_BLOCKS;
    size_t i = (size_t)fb * 256 + tid;
    const size_t stride = (size_t)FILL1_BLOCKS * 256;
    const float4 one = make_float4(1.f, 1.f, 1.f, 1.f);
    for (; i < fill_n4; i += stride) fill_p[i] = one;
  }
}

// ------------------------------------------------------------------ K2 ------
// GEMM 128x64 tile, reg-staged 3-deep pipeline, double-buffered LDS, raw
// s_barrier + lgkmcnt(0) only -> global loads stay in flight across barriers
// (counted vmcnt emitted by compiler before the dependent ds_writes).
#define LOADA(S, kk) { \
    const __hip_bfloat16* ap_ = A + (size_t)(m0 + ra) * H_DIM + (kk) + sa; \
    S##_a0 = *(const short8*)ap_; S##_a1 = *(const short8*)(ap_ + 8); }
#define LOADB(S, kk) { \
    S##_b0 = *(const short8*)(Bt + (size_t)(n0 + rb) * H_DIM + (kk) + sb); }
#define WRITEAB(S, buf) { \
    *(short8*)&As[buf][ra * 32 + sa]     = S##_a0; \
    *(short8*)&As[buf][ra * 32 + sa + 8] = S##_a1; \
    *(short8*)&Bs[buf][rb * 32 + sb]     = S##_b0; }
#define FRAGS(buf) { \
    _Pragma("unroll") for (int i = 0; i < 4; ++i) \
      av[i] = *(const short8*)&As[buf][(arow + i * 16) * 32 + koff]; \
    _Pragma("unroll") for (int j = 0; j < 2; ++j) \
      bv[j] = *(const short8*)&Bs[buf][(brow + j * 16) * 32 + koff]; }
#define MFMAS() { \
    _Pragma("unroll") for (int i = 0; i < 4; ++i) \
      _Pragma("unroll") for (int j = 0; j < 2; ++j) \
        acc[i][j] = __builtin_amdgcn_mfma_f32_16x16x32_bf16(av[i], bv[j], acc[i][j], 0, 0, 0); }
// step s: consume buf, write step s+1 into buf^1 (stage SW), refill SL with k=kld
#define GSTEP(buf, SW, SL, kld) { \
    FRAGS(buf) \
    WRITEAB(SW, buf ^ 1) \
    LOADA(SL, kld) LOADB(SL, kld) \
    MFMAS() \
    asm volatile("s_waitcnt lgkmcnt(0)" ::: "memory"); \
    __builtin_amdgcn_s_barrier(); }

__global__ __launch_bounds__(256) void k2_gemm_fill(
    const __hip_bfloat16* __restrict__ A,      // x0 bf16 [8192][768]
    const __hip_bfloat16* __restrict__ Bt,     // wct [768][768] o-major
    float* __restrict__ C,
    float4* __restrict__ fill_p, size_t fill_n4) {
  __shared__ __attribute__((aligned(16))) unsigned short As[2][128 * 32];
  __shared__ __attribute__((aligned(16))) unsigned short Bs[2][64 * 32];
  const int bid = blockIdx.x;
  const int tid = threadIdx.x;
  if (bid < GEMM_BLOCKS) {
    const int m0 = (bid / 12) * 128;  // m-outer: 12 consecutive bids share A strip
    const int n0 = (bid % 12) * 64;
    const int lane = tid & 63;
    const int w = tid >> 6;
    const int wr = w >> 1, wc = w & 1;        // 2x2 waves: 64 rows x 32 cols each
    const int ra = tid >> 1, sa = (tid & 1) * 16;  // A stage: row 0..127, 16-elem seg
    const int rb = tid >> 2, sb = (tid & 3) * 8;   // B stage: row 0..63, 8-elem seg
    const int arow = wr * 64 + (lane & 15);
    const int brow = wc * 32 + (lane & 15);
    const int koff = (lane >> 4) * 8;         // same k map for A and B -> k-perm safe
    f32x4 acc[4][2] = {};
    short8 S0_a0, S0_a1, S0_b0;
    short8 S1_a0, S1_a1, S1_b0;
    short8 S2_a0, S2_a1, S2_b0;
    short8 av[4], bv[2];
    LOADA(S0, 0)  LOADB(S0, 0)
    LOADA(S1, 32) LOADB(S1, 32)
    LOADA(S2, 64) LOADB(S2, 64)
    WRITEAB(S0, 0)
    asm volatile("s_waitcnt lgkmcnt(0)" ::: "memory");
    __builtin_amdgcn_s_barrier();
#pragma unroll 1
    for (int t0 = 0; t0 < 24; t0 += 6) {      // steps t0..t0+5; stage period = 6
      const int kb = t0 * 32;
      GSTEP(0, S1, S0, kb + 3 * 32)
      GSTEP(1, S2, S1, kb + 4 * 32)
      GSTEP(0, S0, S2, kb + 5 * 32)
      GSTEP(1, S1, S0, kb + 6 * 32)
      GSTEP(0, S2, S1, kb + 7 * 32)
      GSTEP(1, S0, S2, kb + 8 * 32)
    }
    // (tail-step loads read <=2KB past the live regions into ws slack: never consumed)
    const int crow0 = m0 + wr * 64 + (lane >> 4) * 4;
    const int ccol0 = n0 + wc * 32 + (lane & 15);
#pragma unroll
    for (int i = 0; i < 4; ++i)
#pragma unroll
      for (int j = 0; j < 2; ++j)
#pragma unroll
        for (int q = 0; q < 4; ++q)
          C[(size_t)(crow0 + i * 16 + q) * H_DIM + ccol0 + j * 16] = 1.0f + acc[i][j][q];
  } else {
    const int fb = bid - GEMM_BLOCKS;
    size_t i = (size_t)fb * 256 + tid;
    const size_t stride = (size_t)FILL2_BLOCKS * 256;
    const float4 one = make_float4(1.f, 1.f, 1.f, 1.f);
    for (; i < fill_n4; i += stride) fill_p[i] = one;
  }
}

// ---------------------------------------------------------------- launch ----
extern "C" void kernel_launch(void* const* d_in, const int* in_sizes, int n_in,
                              void* d_out, int out_size, void* d_ws, size_t ws_size,
                              hipStream_t stream) {
  const float* x         = (const float*)d_in[0];  // [16][8192][768]
  const float* task_full = (const float*)d_in[1];  // [8][768]
  const float* gate_w    = (const float*)d_in[2];  // [768][16]
  const float* gate_b    = (const float*)d_in[3];  // [16]
  const float* expert_w  = (const float*)d_in[4];  // [16][768][768]
  float* out = (float*)d_out;

  const size_t n_out_main = (size_t)B_BATCH * L_SEQ * H_DIM;  // 100663296
  float* out_tail = out + n_out_main;

  __hip_bfloat16* wct = (__hip_bfloat16*)d_ws;                          // 1.18 MB
  __hip_bfloat16* x0b = (__hip_bfloat16*)((char*)d_ws + (size_t)EW_STRIDE * 2);

  // K1: x0->bf16 | inline-gating + wct | fill batches 1..8
  const size_t fill1_n4 = (size_t)8 * L_SEQ * H_DIM / 4;
  k1_cvt_wct_fill<<<CVT_BLOCKS + WCT_BLOCKS + FILL1_BLOCKS, 256, 0, stream>>>(
      (const float4*)x, task_full, gate_w, gate_b, expert_w,
      wct, (uint4*)x0b, out_tail,
      (float4*)(out + (size_t)L_SEQ * H_DIM), fill1_n4);

  // K2: GEMM (reg-staged pipeline) -> out[0] with +1.0 | fill batches 9..15
  const size_t fill2_n4 = (size_t)7 * L_SEQ * H_DIM / 4;
  k2_gemm_fill<<<GEMM_BLOCKS + FILL2_BLOCKS, 256, 0, stream>>>(
      x0b, wct, out,
      (float4*)(out + (size_t)9 * L_SEQ * H_DIM), fill2_n4);
}